// Round 1
// baseline (8497.053 us; speedup 1.0000x reference)
//
#include <hip/hip_runtime.h>
#include <math.h>

#define BATCH 64
#define PIX   196
#define ENCD  2048
#define DECD  512
#define ATTD  512
#define EMBD  512
#define VOC   10000
#define LCAP  52
#define TSTEPS 51
#define XDIM  2560   // EMBD + ENCD

// ---------------- setup: stable descending argsort + int outputs ----------------
__global__ void k_setup(const int* caps, const int* lens,
                        int* order, int* declen,
                        float* caps_out, float* declen_out, float* order_out) {
    __shared__ int sl[64];
    __shared__ int so[64];
    int tid = threadIdx.x;
    sl[tid] = lens[tid];
    __syncthreads();
    int li = sl[tid];
    int pos = 0;
    for (int j = 0; j < 64; ++j) {
        int lj = sl[j];
        if (lj > li || (lj == li && j < tid)) pos++;
    }
    so[pos] = tid;
    __syncthreads();
    int ob = so[tid];
    order[tid] = ob;
    int dl = sl[ob] - 1;
    declen[tid] = dl;
    order_out[tid] = (float)ob;
    declen_out[tid] = (float)dl;
    for (int l = 0; l < LCAP; ++l)
        caps_out[tid * LCAP + l] = (float)caps[ob * LCAP + l];
}

// ---------------- mean over pixels (sorted order) ----------------
__global__ void k_mean(const float* enc, const int* order, float* meanv) {
    int b = blockIdx.x;
    int col = blockIdx.y * 256 + threadIdx.x;
    int ob = order[b];
    const float* base = enc + (size_t)ob * PIX * ENCD + col;
    float acc = 0.f;
    for (int p = 0; p < PIX; ++p) acc += base[(size_t)p * ENCD];
    meanv[b * ENCD + col] = acc * (1.0f / (float)PIX);
}

// ---------------- h0/c0 = mean @ W + b ----------------
__global__ void k_h0c0(const float* meanv, const float* WH, const float* bH,
                       const float* WC, const float* bC, float* h, float* c) {
    __shared__ float sm[ENCD];
    int b = blockIdx.x, tid = threadIdx.x;
    for (int i = tid; i < ENCD; i += 256) sm[i] = meanv[b * ENCD + i];
    __syncthreads();
    for (int rep = 0; rep < 2; ++rep) {
        int j = rep * 256 + tid;
        float aH = 0.f, aC = 0.f;
        for (int k = 0; k < ENCD; ++k) {
            float m = sm[k];
            aH += m * WH[k * DECD + j];
            aC += m * WC[k * DECD + j];
        }
        h[b * DECD + j] = aH + bH[j];
        c[b * DECD + j] = aC + bC[j];
    }
}

// ---------------- att1 = enc_sorted @ att_enc_W + b  (12544 x 512, K=2048) ----------------
__global__ __launch_bounds__(256) void k_att1(const float* enc, const int* order,
                                              const float* W, const float* bias,
                                              float* att1) {
    __shared__ float As[64][33];
    __shared__ float Bs[32][65];
    __shared__ int rbase[64];
    int rt = blockIdx.x, ct = blockIdx.y, tid = threadIdx.x;
    int a0 = ct * 64;
    if (tid < 64) {
        int r = rt * 64 + tid;
        int b = r / PIX, p = r % PIX;
        rbase[tid] = (order[b] * PIX + p) * ENCD;
    }
    __syncthreads();
    float acc[4][4] = {};
    int tr = tid % 16, tc = tid / 16;
    for (int k0 = 0; k0 < ENCD; k0 += 32) {
        for (int idx = tid; idx < 512; idx += 256) {
            int rl = idx / 8, k4 = (idx % 8) * 4;
            float4 v = *(const float4*)(enc + (size_t)rbase[rl] + k0 + k4);
            As[rl][k4] = v.x; As[rl][k4 + 1] = v.y; As[rl][k4 + 2] = v.z; As[rl][k4 + 3] = v.w;
        }
        for (int idx = tid; idx < 512; idx += 256) {
            int k = idx / 16, a4 = (idx % 16) * 4;
            float4 v = *(const float4*)(W + (size_t)(k0 + k) * ATTD + a0 + a4);
            Bs[k][a4] = v.x; Bs[k][a4 + 1] = v.y; Bs[k][a4 + 2] = v.z; Bs[k][a4 + 3] = v.w;
        }
        __syncthreads();
        for (int kk = 0; kk < 32; ++kk) {
            float a[4], bb[4];
            for (int i = 0; i < 4; ++i) a[i] = As[tr * 4 + i][kk];
            for (int i = 0; i < 4; ++i) bb[i] = Bs[kk][tc * 4 + i];
            for (int i = 0; i < 4; ++i)
                for (int j2 = 0; j2 < 4; ++j2) acc[i][j2] += a[i] * bb[j2];
        }
        __syncthreads();
    }
    int r0 = rt * 64;
    for (int i = 0; i < 4; ++i)
        for (int j2 = 0; j2 < 4; ++j2) {
            int r = r0 + tr * 4 + i, a = a0 + tc * 4 + j2;
            att1[(size_t)r * ATTD + a] = acc[i][j2] + bias[a];
        }
}

// ---------------- per step: att2 = h@Wad+b ; gate = sigmoid(h@Wfb+b) ; x[:,:512]=emb ----------------
__global__ void k_att2gate(const float* h, const float* Wad, const float* bad,
                           const float* Wfb, const float* bfb,
                           const float* embW, const int* caps, const int* order,
                           float* att2, float* gate, float* x, int t) {
    __shared__ float Hs[8][64];
    int jt = blockIdx.x, bg = blockIdx.y, tid = threadIdx.x;
    int j = jt * 256 + tid;   // 0..2559 ; j<512 -> att2, else gate col j-512
    float acc[8] = {};
    for (int k0 = 0; k0 < DECD; k0 += 64) {
        for (int idx = tid; idx < 512; idx += 256) {
            int bb = idx / 64, kk = idx % 64;
            Hs[bb][kk] = h[(bg * 8 + bb) * DECD + k0 + kk];
        }
        __syncthreads();
        if (j < 512) {
            for (int kk = 0; kk < 64; ++kk) {
                float w = Wad[(k0 + kk) * ATTD + j];
                for (int bb = 0; bb < 8; ++bb) acc[bb] += w * Hs[bb][kk];
            }
        } else {
            int jj = j - 512;
            for (int kk = 0; kk < 64; ++kk) {
                float w = Wfb[(size_t)(k0 + kk) * ENCD + jj];
                for (int bb = 0; bb < 8; ++bb) acc[bb] += w * Hs[bb][kk];
            }
        }
        __syncthreads();
    }
    if (j < 512) {
        float bv = bad[j];
        for (int bb = 0; bb < 8; ++bb)
            att2[(bg * 8 + bb) * ATTD + j] = acc[bb] + bv;
    } else {
        int jj = j - 512;
        float bv = bfb[jj];
        for (int bb = 0; bb < 8; ++bb)
            gate[(bg * 8 + bb) * ENCD + jj] = 1.f / (1.f + expf(-(acc[bb] + bv)));
    }
    if (jt == 0) {
        for (int bb = 0; bb < 8; ++bb) {
            int b = bg * 8 + bb;
            int tok = caps[order[b] * LCAP + t];
            for (int idx = tid; idx < EMBD; idx += 256)
                x[b * XDIM + idx] = embW[(size_t)tok * EMBD + idx];
        }
    }
}

// ---------------- e[b,p] = relu(att1[b,p,:] + att2[b,:]) . wfull + bfull ----------------
__global__ void k_e(const float* att1, const float* att2, const float* wfull,
                    const float* bfull, float* e) {
    int b = blockIdx.x;
    int p = blockIdx.y * 4 + threadIdx.x / 64;
    int lane = threadIdx.x % 64;
    const float* a1 = att1 + ((size_t)b * PIX + p) * ATTD;
    const float* a2 = att2 + b * ATTD;
    float acc = 0.f;
    for (int i = 0; i < 8; ++i) {
        int a = i * 64 + lane;
        float v = a1[a] + a2[a];
        v = v > 0.f ? v : 0.f;
        acc += v * wfull[a];
    }
    for (int off = 32; off > 0; off >>= 1) acc += __shfl_down(acc, off);
    if (lane == 0) e[b * PIX + p] = acc + bfull[0];
}

// ---------------- softmax(e) -> alpha ; awe ; x[:,512:]=gate*awe ; write alphas out ----------------
__global__ void k_awe(const float* e, const float* enc, const int* order,
                      const float* gate, const int* declen,
                      float* x, float* alphas_out, int t) {
    __shared__ float sred[256];
    __shared__ float sAlpha[256];
    int b = blockIdx.x, et = blockIdx.y, tid = threadIdx.x;
    float ev = (tid < PIX) ? e[b * PIX + tid] : -1e30f;
    sred[tid] = ev;
    __syncthreads();
    for (int s = 128; s > 0; s >>= 1) {
        if (tid < s) sred[tid] = fmaxf(sred[tid], sred[tid + s]);
        __syncthreads();
    }
    float m = sred[0];
    __syncthreads();
    float pv = (tid < PIX) ? expf(ev - m) : 0.f;
    sred[tid] = pv;
    __syncthreads();
    for (int s = 128; s > 0; s >>= 1) {
        if (tid < s) sred[tid] += sred[tid + s];
        __syncthreads();
    }
    float inv = 1.f / sred[0];
    __syncthreads();
    sAlpha[tid] = pv * inv;
    __syncthreads();
    int col = et * 256 + tid;
    int ob = order[b];
    const float* base = enc + (size_t)ob * PIX * ENCD + col;
    float acc = 0.f;
    for (int p = 0; p < PIX; ++p) acc += sAlpha[p] * base[(size_t)p * ENCD];
    x[b * XDIM + EMBD + col] = gate[b * ENCD + col] * acc;
    if (et == 0 && tid < PIX) {
        bool mask = t < declen[b];
        alphas_out[((size_t)b * TSTEPS + t) * PIX + tid] = mask ? sAlpha[tid] : 0.f;
    }
}

// ---------------- gates partial GEMM: partial[kc] = Achunk @ Wchunk^T ----------------
__global__ __launch_bounds__(256) void k_gates(const float* x, const float* h,
                                               const float* Wih, const float* Whh,
                                               float* partial) {
    __shared__ float As[64][33];
    __shared__ float Bs[32][65];
    int jt = blockIdx.x, kc = blockIdx.y, tid = threadIdx.x;
    int j0 = jt * 64;
    const float* A; int sA; const float* Bp; int sB;
    if (kc < 5) { A = x + kc * 512; sA = XDIM; Bp = Wih + kc * 512; sB = XDIM; }
    else        { A = h;            sA = DECD; Bp = Whh;            sB = DECD; }
    float acc[4][4] = {};
    int tr = tid % 16, tc = tid / 16;
    for (int k0 = 0; k0 < 512; k0 += 32) {
        for (int idx = tid; idx < 512; idx += 256) {
            int rl = idx / 8, k4 = (idx % 8) * 4;
            float4 v = *(const float4*)(A + (size_t)rl * sA + k0 + k4);
            As[rl][k4] = v.x; As[rl][k4 + 1] = v.y; As[rl][k4 + 2] = v.z; As[rl][k4 + 3] = v.w;
        }
        for (int idx = tid; idx < 512; idx += 256) {
            int jl = idx / 8, k4 = (idx % 8) * 4;
            float4 v = *(const float4*)(Bp + (size_t)(j0 + jl) * sB + k0 + k4);
            Bs[k4][jl] = v.x; Bs[k4 + 1][jl] = v.y; Bs[k4 + 2][jl] = v.z; Bs[k4 + 3][jl] = v.w;
        }
        __syncthreads();
        for (int kk = 0; kk < 32; ++kk) {
            float a[4], bb[4];
            for (int i = 0; i < 4; ++i) a[i] = As[tr * 4 + i][kk];
            for (int i = 0; i < 4; ++i) bb[i] = Bs[kk][tc * 4 + i];
            for (int i = 0; i < 4; ++i)
                for (int j2 = 0; j2 < 4; ++j2) acc[i][j2] += a[i] * bb[j2];
        }
        __syncthreads();
    }
    float* out = partial + (size_t)kc * (64 * 2048);
    for (int i = 0; i < 4; ++i)
        for (int j2 = 0; j2 < 4; ++j2)
            out[(tr * 4 + i) * 2048 + j0 + tc * 4 + j2] = acc[i][j2];
}

// ---------------- LSTM pointwise update ----------------
__global__ void k_update(const float* partial, const float* bih, const float* bhh,
                         const int* declen, float* h, float* c, float* hall, int t) {
    int b = blockIdx.x, d = threadIdx.x;
    float g[4];
    for (int q = 0; q < 4; ++q) {
        int j = q * 512 + d;
        float acc = bih[j] + bhh[j];
        for (int kc = 0; kc < 6; ++kc) acc += partial[(size_t)kc * (64 * 2048) + b * 2048 + j];
        g[q] = acc;
    }
    float si = 1.f / (1.f + expf(-g[0]));
    float sf = 1.f / (1.f + expf(-g[1]));
    float gg = tanhf(g[2]);
    float so = 1.f / (1.f + expf(-g[3]));
    float c_old = c[b * DECD + d], h_old = h[b * DECD + d];
    float c_new = sf * c_old + si * gg;
    float h_new = so * tanhf(c_new);
    bool mask = t < declen[b];
    h[b * DECD + d] = mask ? h_new : h_old;
    c[b * DECD + d] = mask ? c_new : c_old;
    hall[((size_t)t * 64 + b) * DECD + d] = h_new;
}

// ---------------- batched fc: preds[b,t,:] = mask ? hall[t,b,:]@fc_W + fc_b : 0 ----------------
__global__ __launch_bounds__(256) void k_fc(const float* hall, const float* W,
                                            const float* bias, const int* declen,
                                            float* preds) {
    __shared__ float As[64][33];
    __shared__ float Bs[32][65];
    int vt = blockIdx.x, tt = blockIdx.y, tid = threadIdx.x;
    int v0 = vt * 64;
    const float* A = hall + (size_t)tt * 64 * DECD;
    float acc[4][4] = {};
    int tr = tid % 16, tc = tid / 16;
    for (int k0 = 0; k0 < DECD; k0 += 32) {
        for (int idx = tid; idx < 512; idx += 256) {
            int rl = idx / 8, k4 = (idx % 8) * 4;
            float4 v = *(const float4*)(A + (size_t)rl * DECD + k0 + k4);
            As[rl][k4] = v.x; As[rl][k4 + 1] = v.y; As[rl][k4 + 2] = v.z; As[rl][k4 + 3] = v.w;
        }
        for (int idx = tid; idx < 512; idx += 256) {
            int k = idx / 16, v4 = (idx % 16) * 4;
            float4 v = make_float4(0.f, 0.f, 0.f, 0.f);
            if (v0 + v4 + 3 < VOC) v = *(const float4*)(W + (size_t)(k0 + k) * VOC + v0 + v4);
            Bs[k][v4] = v.x; Bs[k][v4 + 1] = v.y; Bs[k][v4 + 2] = v.z; Bs[k][v4 + 3] = v.w;
        }
        __syncthreads();
        for (int kk = 0; kk < 32; ++kk) {
            float a[4], bb[4];
            for (int i = 0; i < 4; ++i) a[i] = As[tr * 4 + i][kk];
            for (int i = 0; i < 4; ++i) bb[i] = Bs[kk][tc * 4 + i];
            for (int i = 0; i < 4; ++i)
                for (int j2 = 0; j2 < 4; ++j2) acc[i][j2] += a[i] * bb[j2];
        }
        __syncthreads();
    }
    for (int i = 0; i < 4; ++i) {
        int b = tr * 4 + i;
        bool mask = tt < declen[b];
        for (int j2 = 0; j2 < 4; ++j2) {
            int v = v0 + tc * 4 + j2;
            if (v < VOC)
                preds[((size_t)b * TSTEPS + tt) * VOC + v] = mask ? (acc[i][j2] + bias[v]) : 0.f;
        }
    }
}

extern "C" void kernel_launch(void* const* d_in, const int* in_sizes, int n_in,
                              void* d_out, int out_size, void* d_ws, size_t ws_size,
                              hipStream_t stream) {
    const float* enc      = (const float*)d_in[0];
    const int*   caps     = (const int*)d_in[1];
    const int*   lens     = (const int*)d_in[2];
    const float* embW     = (const float*)d_in[3];
    const float* att_enc_W = (const float*)d_in[4];
    const float* att_enc_b = (const float*)d_in[5];
    const float* att_dec_W = (const float*)d_in[6];
    const float* att_dec_b = (const float*)d_in[7];
    const float* att_full_w = (const float*)d_in[8];
    const float* att_full_b = (const float*)d_in[9];
    const float* lstm_Wih = (const float*)d_in[10];
    const float* lstm_Whh = (const float*)d_in[11];
    const float* lstm_bih = (const float*)d_in[12];
    const float* lstm_bhh = (const float*)d_in[13];
    const float* initH_W  = (const float*)d_in[14];
    const float* initH_b  = (const float*)d_in[15];
    const float* initC_W  = (const float*)d_in[16];
    const float* initC_b  = (const float*)d_in[17];
    const float* fbeta_W  = (const float*)d_in[18];
    const float* fbeta_b  = (const float*)d_in[19];
    const float* fc_W     = (const float*)d_in[20];
    const float* fc_b     = (const float*)d_in[21];

    // outputs (flat f32): preds | caps | dec_len | alphas | order
    float* o = (float*)d_out;
    float* preds_out  = o;
    float* caps_out   = o + (size_t)BATCH * TSTEPS * VOC;            // 32,640,000
    float* declen_out = caps_out + (size_t)BATCH * LCAP;             // +3,328
    float* order_out  = declen_out + BATCH;                          // +64
    float* alphas_out = order_out + BATCH;                           // +64

    // workspace layout
    char* wsb = (char*)d_ws;
    int* i_order  = (int*)wsb;                 // 64
    int* i_declen = i_order + 64;              // 64
    float* f = (float*)(wsb + 512);
    float* f_mean = f;            f += (size_t)BATCH * ENCD;     // 131072
    float* f_h    = f;            f += (size_t)BATCH * DECD;
    float* f_c    = f;            f += (size_t)BATCH * DECD;
    float* f_att2 = f;            f += (size_t)BATCH * ATTD;
    float* f_gate = f;            f += (size_t)BATCH * ENCD;
    float* f_x    = f;            f += (size_t)BATCH * XDIM;
    float* f_e    = f;            f += (size_t)BATCH * PIX;
    f = (float*)(((uintptr_t)f + 63) & ~(uintptr_t)63);
    float* f_att1 = f;            f += (size_t)BATCH * PIX * ATTD; // 6,422,528
    float* f_part = f;            f += (size_t)6 * BATCH * 2048;
    float* f_hall = f;            f += (size_t)TSTEPS * BATCH * DECD;

    k_setup<<<1, 64, 0, stream>>>(caps, lens, i_order, i_declen,
                                  caps_out, declen_out, order_out);
    k_mean<<<dim3(BATCH, ENCD / 256), 256, 0, stream>>>(enc, i_order, f_mean);
    k_h0c0<<<BATCH, 256, 0, stream>>>(f_mean, initH_W, initH_b, initC_W, initC_b,
                                      f_h, f_c);
    k_att1<<<dim3(196, 8), 256, 0, stream>>>(enc, i_order, att_enc_W, att_enc_b,
                                             f_att1);

    for (int t = 0; t < TSTEPS; ++t) {
        k_att2gate<<<dim3(10, 8), 256, 0, stream>>>(f_h, att_dec_W, att_dec_b,
                                                    fbeta_W, fbeta_b, embW, caps,
                                                    i_order, f_att2, f_gate, f_x, t);
        k_e<<<dim3(BATCH, 49), 256, 0, stream>>>(f_att1, f_att2, att_full_w,
                                                 att_full_b, f_e);
        k_awe<<<dim3(BATCH, ENCD / 256), 256, 0, stream>>>(f_e, enc, i_order,
                                                           f_gate, i_declen,
                                                           f_x, alphas_out, t);
        k_gates<<<dim3(32, 6), 256, 0, stream>>>(f_x, f_h, lstm_Wih, lstm_Whh,
                                                 f_part);
        k_update<<<BATCH, DECD, 0, stream>>>(f_part, lstm_bih, lstm_bhh, i_declen,
                                             f_h, f_c, f_hall, t);
    }

    k_fc<<<dim3((VOC + 63) / 64, TSTEPS), 256, 0, stream>>>(f_hall, fc_W, fc_b,
                                                            i_declen, preds_out);
}